// Round 7
// baseline (560.989 us; speedup 1.0000x reference)
//
#include <hip/hip_runtime.h>

// Problem constants
#define DIM_   512
#define NSEQ   1024
#define BB     16
#define HH     16
#define KD_    32
#define DD_    128
#define DH_    2048   // H*D
#define SCALE_ 0.17677669529663687f  // 32^-0.5

typedef __bf16 bf16x8 __attribute__((ext_vector_type(8)));
typedef float  f32x4  __attribute__((ext_vector_type(4)));

typedef __attribute__((address_space(1))) const unsigned int guint;
typedef __attribute__((address_space(3))) unsigned int luint;
#define GLL16(gp, lp) __builtin_amdgcn_global_load_lds((guint*)(gp), (luint*)(lp), 16, 0, 0)

static __device__ __forceinline__ unsigned short f2bf(float f) {
  unsigned int u = __builtin_bit_cast(unsigned int, f);
  u += 0x7fffu + ((u >> 16) & 1u);   // round-to-nearest-even
  return (unsigned short)(u >> 16);
}
// key-within-group permutation (R5/R6 hardware-verified): applied once in vtrans,
// matched by p_sm writes + PV reads in attn.
#define SGM(t) ((((t) & 3) << 1) | (((t) >> 2) & 1))

// ---------------- fp32 -> bf16 convert ----------------
__global__ __launch_bounds__(256) void cvt_kernel(const float* __restrict__ in,
                                                  unsigned short* __restrict__ out,
                                                  int n) {
  int i = blockIdx.x * 256 + threadIdx.x;
  if (i < n) out[i] = f2bf(in[i]);
}

// ---------------- LayerNorm (fp32 in) -> bf16 out ----------------
__global__ __launch_bounds__(256) void ln_kernel(const float* __restrict__ x,
                                                 const float* __restrict__ gamma,
                                                 const float* __restrict__ beta,
                                                 unsigned short* __restrict__ xn) {
  int row = blockIdx.x, t = threadIdx.x;
  const float* xr = x + (size_t)row * DIM_;
  float2 v = *(const float2*)(xr + t * 2);
  float s = v.x + v.y, sq = v.x * v.x + v.y * v.y;
#pragma unroll
  for (int off = 32; off; off >>= 1) {
    s  += __shfl_xor(s, off, 64);
    sq += __shfl_xor(sq, off, 64);
  }
  __shared__ float red[8];
  int wid = t >> 6, lane = t & 63;
  if (lane == 0) { red[wid * 2] = s; red[wid * 2 + 1] = sq; }
  __syncthreads();
  float S  = red[0] + red[2] + red[4] + red[6];
  float SQ = red[1] + red[3] + red[5] + red[7];
  float mu   = S * (1.f / DIM_);
  float var  = SQ * (1.f / DIM_) - mu * mu;
  float rstd = rsqrtf(var + 1e-5f);
  int c = t * 2;
  xn[(size_t)row * DIM_ + c]     = f2bf((v.x - mu) * rstd * gamma[c]     + beta[c]);
  xn[(size_t)row * DIM_ + c + 1] = f2bf((v.y - mu) * rstd * gamma[c + 1] + beta[c + 1]);
}

// ---------------- QKV GEMM with global_load_lds staging, split Q/K vs V store -------
// A:(16384 x 512) xn, W:(3072 x 512) wqkv. col -> h=col/192, off=col%192:
// off<64 -> qk[row*1024 + h*64 + off]; else vrow[row*2048 + h*128 + off-64].
__global__ __launch_bounds__(256) void gemm_qkv(const unsigned short* __restrict__ A,
                                                const unsigned short* __restrict__ W,
                                                const float* __restrict__ bias,
                                                unsigned short* __restrict__ qk,
                                                unsigned short* __restrict__ vrow) {
  __shared__ unsigned short a_sm[128][64];
  __shared__ unsigned short b_sm[128][64];
  int tid = threadIdx.x;
  int lane = tid & 63, w = tid >> 6;
  int quad = lane >> 4, l15 = lane & 15;
  int wr = w >> 1, wc = w & 1;
  long tm = (long)blockIdx.y * 128, tn = (long)blockIdx.x * 128;
  int srow = w * 8 + (lane >> 3), scol = (lane & 7) * 8;

  f32x4 acc[4][4] = {};

  for (int k0 = 0; k0 < 512; k0 += 64) {
    __syncthreads();
#pragma unroll
    for (int it = 0; it < 4; it++) {
      GLL16(A + (tm + it * 32 + srow) * 512 + k0 + scol, &a_sm[it * 32 + w * 8][0]);
      GLL16(W + (tn + it * 32 + srow) * 512 + k0 + scol, &b_sm[it * 32 + w * 8][0]);
    }
    __syncthreads();
#pragma unroll
    for (int kk = 0; kk < 64; kk += 32) {
      bf16x8 af[4], bfr[4];
#pragma unroll
      for (int i = 0; i < 4; i++)
        af[i] = *(const bf16x8*)&a_sm[wr * 64 + i * 16 + l15][kk + quad * 8];
#pragma unroll
      for (int j = 0; j < 4; j++)
        bfr[j] = *(const bf16x8*)&b_sm[wc * 64 + j * 16 + l15][kk + quad * 8];
#pragma unroll
      for (int i = 0; i < 4; i++)
#pragma unroll
        for (int j = 0; j < 4; j++)
          acc[i][j] = __builtin_amdgcn_mfma_f32_16x16x32_bf16(af[i], bfr[j], acc[i][j], 0, 0, 0);
    }
  }
#pragma unroll
  for (int j = 0; j < 4; j++) {
    long col = tn + wc * 64 + j * 16 + l15;
    float bv = bias[col];
    int h = (int)(col / 192), off = (int)(col - h * 192);
    long coff = (off < 64) ? (long)h * 64 + off : (long)h * 128 + (off - 64);
    unsigned short* dst = (off < 64) ? qk : vrow;
    long ldo = (off < 64) ? 1024 : 2048;
#pragma unroll
    for (int i = 0; i < 4; i++) {
      long row0 = tm + wr * 64 + i * 16 + quad * 4;
#pragma unroll
      for (int r = 0; r < 4; r++)
        dst[(row0 + r) * ldo + coff] = f2bf(acc[i][j][r] + bv);
    }
  }
}

// ---------------- proj GEMM (fp32 out) with global_load_lds staging -----------------
__global__ __launch_bounds__(256) void gemm_proj(const unsigned short* __restrict__ A,
                                                 const unsigned short* __restrict__ W,
                                                 const float* __restrict__ bias,
                                                 float* __restrict__ C) {
  __shared__ unsigned short a_sm[128][64];
  __shared__ unsigned short b_sm[128][64];
  int tid = threadIdx.x;
  int lane = tid & 63, w = tid >> 6;
  int quad = lane >> 4, l15 = lane & 15;
  int wr = w >> 1, wc = w & 1;
  long tm = (long)blockIdx.y * 128, tn = (long)blockIdx.x * 128;
  int srow = w * 8 + (lane >> 3), scol = (lane & 7) * 8;

  f32x4 acc[4][4] = {};

  for (int k0 = 0; k0 < 2048; k0 += 64) {
    __syncthreads();
#pragma unroll
    for (int it = 0; it < 4; it++) {
      GLL16(A + (tm + it * 32 + srow) * 2048 + k0 + scol, &a_sm[it * 32 + w * 8][0]);
      GLL16(W + (tn + it * 32 + srow) * 2048 + k0 + scol, &b_sm[it * 32 + w * 8][0]);
    }
    __syncthreads();
#pragma unroll
    for (int kk = 0; kk < 64; kk += 32) {
      bf16x8 af[4], bfr[4];
#pragma unroll
      for (int i = 0; i < 4; i++)
        af[i] = *(const bf16x8*)&a_sm[wr * 64 + i * 16 + l15][kk + quad * 8];
#pragma unroll
      for (int j = 0; j < 4; j++)
        bfr[j] = *(const bf16x8*)&b_sm[wc * 64 + j * 16 + l15][kk + quad * 8];
#pragma unroll
      for (int i = 0; i < 4; i++)
#pragma unroll
        for (int j = 0; j < 4; j++)
          acc[i][j] = __builtin_amdgcn_mfma_f32_16x16x32_bf16(af[i], bfr[j], acc[i][j], 0, 0, 0);
    }
  }
#pragma unroll
  for (int j = 0; j < 4; j++) {
    long col = tn + wc * 64 + j * 16 + l15;
    float bv = bias[col];
#pragma unroll
    for (int i = 0; i < 4; i++) {
      long row0 = tm + wr * 64 + i * 16 + quad * 4;
#pragma unroll
      for (int r = 0; r < 4; r++)
        C[(row0 + r) * 512 + col] = acc[i][j][r] + bv;
    }
  }
}

// ---------------- V transpose: vrow[row][h*128+d] -> vtg[bh][d][key'] ----------------
// Uses the R6-verified SGM-swizzled LDS transpose once per (bh, key-tile).
__global__ __launch_bounds__(256) void vtrans_kernel(const unsigned short* __restrict__ vrow,
                                                     unsigned short* __restrict__ vtg) {
  __shared__ unsigned short vt[128][72];
  int tid = threadIdx.x;
  int kt = blockIdx.x, bh = blockIdx.y;
  int b = bh >> 4, h = bh & 15;
  const unsigned short* base = vrow + (size_t)b * NSEQ * DH_ + h * 128;
#pragma unroll
  for (int i = 0; i < 4; i++) {
    int c = tid + i * 256;
    int m = c >> 4, c8 = c & 15;
    uint4 vv = *(const uint4*)(base + (size_t)(kt * 64 + m) * DH_ + c8 * 8);
    const unsigned short* pv = (const unsigned short*)&vv;
    int col = (((m >> 3) ^ (c8 & 7)) << 3) | SGM(m & 7);
#pragma unroll
    for (int e = 0; e < 8; e++) vt[c8 * 8 + e][col] = pv[e];
  }
  __syncthreads();
#pragma unroll
  for (int i = 0; i < 4; i++) {
    int c = tid + i * 256;
    int d = c >> 3, k8 = c & 7;
    uint4 vv = *(const uint4*)&vt[d][k8 * 8];
    *(uint4*)(vtg + ((size_t)bh * 128 + d) * NSEQ + kt * 64 + k8 * 8) = vv;
  }
}

// ---------------- Flash attention v4: pre-transposed V, 2q x 2d PV split -------------
__global__ __launch_bounds__(256) void attn_kernel(const unsigned short* __restrict__ qk,
                                                   const unsigned short* __restrict__ vtg,
                                                   const float* __restrict__ ab,
                                                   unsigned short* __restrict__ attn_out) {
  __shared__ float lut[1024];
  __shared__ unsigned short vt[128][72];      // V^T tile (swizzled key cols)
  __shared__ unsigned short k_sm[64][40];
  __shared__ unsigned short p_sm[4][16][72];
  __shared__ float l_sm[64];

  int tid = threadIdx.x;
  int lane = tid & 63, w = tid >> 6;
  int quad = lane >> 4, l15 = lane & 15;
  int wq = w & 1, wd = w >> 1;
  int qb = blockIdx.x;
  int bh = blockIdx.y;
  int b = bh >> 4, h = bh & 15;
  const unsigned short* qkb = qk + (size_t)b * NSEQ * 1024 + h * 64;
  const unsigned short* vb  = vtg + (size_t)bh * 128 * NSEQ;

  for (int t = tid; t < 1024; t += 256) lut[t] = ab[h * 1024 + t];

  // Q fragment: A[m=lane&15][k=quad*8+j]
  int qr = qb * 64 + w * 16 + l15;
  bf16x8 qf = *(const bf16x8*)(qkb + (size_t)qr * 1024 + quad * 8);

  f32x4 accO[2][4] = {};
  float l_r[4] = {0.f, 0.f, 0.f, 0.f};

  int pcol_lo = (l15 & 8) | SGM(l15 & 7);
  int kkey = tid >> 2, kch = tid & 3;
  int vd = tid >> 3, vk8 = tid & 7;            // V staging coords (b128)

  // prologue prefetch (tile 0)
  uint4 vreg[4];
  uint4 kreg;
#pragma unroll
  for (int i = 0; i < 4; i++)
    vreg[i] = *(const uint4*)(vb + (size_t)(vd + i * 32) * NSEQ + vk8 * 8);
  kreg = *(const uint4*)(qkb + (size_t)kkey * 1024 + 32 + kch * 8);

  for (int kt = 0; kt < 16; kt++) {
    __syncthreads();  // prior tile's readers done
#pragma unroll
    for (int i = 0; i < 4; i++)
      *(uint4*)&vt[vd + i * 32][vk8 * 8] = vreg[i];
    *(uint4*)&k_sm[kkey][kch * 8] = kreg;
    __syncthreads();  // staged

    if (kt < 15) {
#pragma unroll
      for (int i = 0; i < 4; i++)
        vreg[i] = *(const uint4*)(vb + (size_t)(vd + i * 32) * NSEQ + (kt + 1) * 64 + vk8 * 8);
      kreg = *(const uint4*)(qkb + (size_t)((kt + 1) * 64 + kkey) * 1024 + 32 + kch * 8);
    }

    // S = Q K^T
    f32x4 s[4];
#pragma unroll
    for (int nb = 0; nb < 4; nb++) {
      bf16x8 kf = *(const bf16x8*)&k_sm[nb * 16 + l15][quad * 8];
      f32x4 z = {};
      s[nb] = __builtin_amdgcn_mfma_f32_16x16x32_bf16(qf, kf, z, 0, 0, 0);
    }

    // scale + analytic bias + exp; l partials; write P (SGM-permuted cols)
#pragma unroll
    for (int nb = 0; nb < 4; nb++) {
      int cc = kt * 64 + nb * 16 + l15;
      int cx = cc >> 5, cy = cc & 31;
#pragma unroll
      for (int r = 0; r < 4; r++) {
        int rr = qb * 64 + w * 16 + quad * 4 + r;
        int dx = (rr >> 5) - cx; dx = dx < 0 ? -dx : dx;
        int dy = (rr & 31) - cy; dy = dy < 0 ? -dy : dy;
        float p = __expf(fmaf(s[nb][r], SCALE_, lut[dx * 32 + dy]));
        l_r[r] += p;
        p_sm[w][quad * 4 + r][nb * 16 + pcol_lo] = f2bf(p);
      }
    }
    __syncthreads();  // p_sm visible

    // O += P V : wave (wq, wd) covers q-groups {2wq, 2wq+1} x d-blocks {4wd..4wd+3}
#pragma unroll
    for (int kc = 0; kc < 2; kc++) {
      bf16x8 pf[2];
#pragma unroll
      for (int g = 0; g < 2; g++)
        pf[g] = *(const bf16x8*)&p_sm[wq * 2 + g][l15][kc * 32 + quad * 8];
#pragma unroll
      for (int j = 0; j < 4; j++) {
        int db = wd * 4 + j;
        int f = (db * 2 + (l15 >> 3)) & 7;
        int colb = ((kc * 4 + quad) ^ f) << 3;
        bf16x8 vf = *(const bf16x8*)&vt[db * 16 + l15][colb];
#pragma unroll
        for (int g = 0; g < 2; g++)
          accO[g][j] = __builtin_amdgcn_mfma_f32_16x16x32_bf16(pf[g], vf, accO[g][j], 0, 0, 0);
      }
    }
  }
  // share l across waves (wave w computed rows w*16..+16)
#pragma unroll
  for (int r = 0; r < 4; r++) {
#pragma unroll
    for (int off = 8; off; off >>= 1) l_r[r] += __shfl_xor(l_r[r], off, 16);
  }
  if (l15 == 0) {
#pragma unroll
    for (int r = 0; r < 4; r++) l_sm[w * 16 + quad * 4 + r] = l_r[r];
  }
  __syncthreads();
  // epilogue
#pragma unroll
  for (int g = 0; g < 2; g++) {
#pragma unroll
    for (int r = 0; r < 4; r++) {
      int row16 = (wq * 2 + g) * 16 + quad * 4 + r;
      float inv = 1.f / l_sm[row16];
      int row = qb * 64 + row16;
      size_t obase = ((size_t)b * NSEQ + row) * DH_ + h * DD_;
#pragma unroll
      for (int j = 0; j < 4; j++)
        attn_out[obase + (wd * 4 + j) * 16 + l15] = f2bf(accO[g][j][r] * inv);
    }
  }
}

extern "C" void kernel_launch(void* const* d_in, const int* in_sizes, int n_in,
                              void* d_out, int out_size, void* d_ws, size_t ws_size,
                              hipStream_t stream) {
  const float* x      = (const float*)d_in[0];
  const float* gamma  = (const float*)d_in[1];
  const float* beta   = (const float*)d_in[2];
  const float* qkv_w  = (const float*)d_in[3];
  const float* qkv_b  = (const float*)d_in[4];
  const float* proj_w = (const float*)d_in[5];
  const float* proj_b = (const float*)d_in[6];
  const float* ab     = (const float*)d_in[7];

  char* ws = (char*)d_ws;
  unsigned short* xn    = (unsigned short*)(ws);                           // 16 MiB @0
  unsigned short* wqkv  = (unsigned short*)(ws + (size_t)16 * 1048576);    //  3 MiB @16
  unsigned short* wproj = (unsigned short*)(ws + (size_t)19 * 1048576);    //  2 MiB @19
  unsigned short* qkbuf = (unsigned short*)(ws + (size_t)21 * 1048576);    // 32 MiB @21
  unsigned short* vrow  = (unsigned short*)(ws + (size_t)53 * 1048576);    // 64 MiB @53 (dead after vtrans)
  unsigned short* attno = vrow;                                            // reuse @53
  unsigned short* vtg   = (unsigned short*)(ws + (size_t)117 * 1048576);   // 64 MiB @117
  float* out = (float*)d_out;                                              // fp32 output

  cvt_kernel<<<dim3(6144), dim3(256), 0, stream>>>(qkv_w, wqkv, 3072 * 512);
  cvt_kernel<<<dim3(4096), dim3(256), 0, stream>>>(proj_w, wproj, 512 * 2048);
  ln_kernel<<<dim3(16384), dim3(256), 0, stream>>>(x, gamma, beta, xn);
  gemm_qkv<<<dim3(24, 128), dim3(256), 0, stream>>>(xn, wqkv, qkv_b, qkbuf, vrow);
  vtrans_kernel<<<dim3(16, 256), dim3(256), 0, stream>>>(vrow, vtg);
  attn_kernel<<<dim3(16, 256), dim3(256), 0, stream>>>(qkbuf, vtg, ab, attno);
  gemm_proj<<<dim3(4, 128), dim3(256), 0, stream>>>(attno, wproj, proj_b, out);
}

// Round 8
// 446.066 us; speedup vs baseline: 1.2576x; 1.2576x over previous
//
#include <hip/hip_runtime.h>

// Problem constants
#define DIM_   512
#define NSEQ   1024
#define BB     16
#define HH     16
#define KD_    32
#define DD_    128
#define LDQKV  3072   // H*(2*KD+D)
#define DH_    2048   // H*D
#define SCALE_ 0.17677669529663687f  // 32^-0.5

typedef __bf16 bf16x8 __attribute__((ext_vector_type(8)));
typedef float  f32x4  __attribute__((ext_vector_type(4)));

typedef __attribute__((address_space(1))) const unsigned int guint;
typedef __attribute__((address_space(3))) unsigned int luint;
#define GLL16(gp, lp) __builtin_amdgcn_global_load_lds((guint*)(gp), (luint*)(lp), 16, 0, 0)

static __device__ __forceinline__ unsigned short f2bf(float f) {
  unsigned int u = __builtin_bit_cast(unsigned int, f);
  u += 0x7fffu + ((u >> 16) & 1u);   // round-to-nearest-even
  return (unsigned short)(u >> 16);
}
// key-within-group permutation (R5/R6 HW-verified), matched in p_sm + PV reads.
#define SGM(t) ((((t) & 3) << 1) | (((t) >> 2) & 1))

// ---------------- fp32 -> bf16 convert ----------------
__global__ __launch_bounds__(256) void cvt_kernel(const float* __restrict__ in,
                                                  unsigned short* __restrict__ out,
                                                  int n) {
  int i = blockIdx.x * 256 + threadIdx.x;
  if (i < n) out[i] = f2bf(in[i]);
}

// ---------------- LayerNorm (fp32 in) -> bf16 out ----------------
__global__ __launch_bounds__(256) void ln_kernel(const float* __restrict__ x,
                                                 const float* __restrict__ gamma,
                                                 const float* __restrict__ beta,
                                                 unsigned short* __restrict__ xn) {
  int row = blockIdx.x, t = threadIdx.x;
  const float* xr = x + (size_t)row * DIM_;
  float2 v = *(const float2*)(xr + t * 2);
  float s = v.x + v.y, sq = v.x * v.x + v.y * v.y;
#pragma unroll
  for (int off = 32; off; off >>= 1) {
    s  += __shfl_xor(s, off, 64);
    sq += __shfl_xor(sq, off, 64);
  }
  __shared__ float red[8];
  int wid = t >> 6, lane = t & 63;
  if (lane == 0) { red[wid * 2] = s; red[wid * 2 + 1] = sq; }
  __syncthreads();
  float S  = red[0] + red[2] + red[4] + red[6];
  float SQ = red[1] + red[3] + red[5] + red[7];
  float mu   = S * (1.f / DIM_);
  float var  = SQ * (1.f / DIM_) - mu * mu;
  float rstd = rsqrtf(var + 1e-5f);
  int c = t * 2;
  xn[(size_t)row * DIM_ + c]     = f2bf((v.x - mu) * rstd * gamma[c]     + beta[c]);
  xn[(size_t)row * DIM_ + c + 1] = f2bf((v.y - mu) * rstd * gamma[c + 1] + beta[c + 1]);
}

// ---------------- GEMM (GLL staging, bf16/fp32 out): C = A*W^T + bias ----------------
template <typename OUT>
__global__ __launch_bounds__(256) void gemm_gll(const unsigned short* __restrict__ A, int lda,
                                                const unsigned short* __restrict__ W, int ldb,
                                                const float* __restrict__ bias,
                                                OUT* __restrict__ C, int ldc,
                                                int K) {
  __shared__ unsigned short a_sm[128][64];
  __shared__ unsigned short b_sm[128][64];
  int tid = threadIdx.x;
  int lane = tid & 63, w = tid >> 6;
  int quad = lane >> 4, l15 = lane & 15;
  int wr = w >> 1, wc = w & 1;
  long tm = (long)blockIdx.y * 128, tn = (long)blockIdx.x * 128;
  int srow = w * 8 + (lane >> 3), scol = (lane & 7) * 8;

  f32x4 acc[4][4] = {};

  for (int k0 = 0; k0 < K; k0 += 64) {
    __syncthreads();
#pragma unroll
    for (int it = 0; it < 4; it++) {
      GLL16(A + (tm + it * 32 + srow) * lda + k0 + scol, &a_sm[it * 32 + w * 8][0]);
      GLL16(W + (tn + it * 32 + srow) * ldb + k0 + scol, &b_sm[it * 32 + w * 8][0]);
    }
    __syncthreads();
#pragma unroll
    for (int kk = 0; kk < 64; kk += 32) {
      bf16x8 af[4], bfr[4];
#pragma unroll
      for (int i = 0; i < 4; i++)
        af[i] = *(const bf16x8*)&a_sm[wr * 64 + i * 16 + l15][kk + quad * 8];
#pragma unroll
      for (int j = 0; j < 4; j++)
        bfr[j] = *(const bf16x8*)&b_sm[wc * 64 + j * 16 + l15][kk + quad * 8];
#pragma unroll
      for (int i = 0; i < 4; i++)
#pragma unroll
        for (int j = 0; j < 4; j++)
          acc[i][j] = __builtin_amdgcn_mfma_f32_16x16x32_bf16(af[i], bfr[j], acc[i][j], 0, 0, 0);
    }
  }
#pragma unroll
  for (int j = 0; j < 4; j++) {
    long col = tn + wc * 64 + j * 16 + l15;
    float bv = bias[col];
#pragma unroll
    for (int i = 0; i < 4; i++) {
      long row0 = tm + wr * 64 + i * 16 + quad * 4;
#pragma unroll
      for (int r = 0; r < 4; r++) {
        float val = acc[i][j][r] + bv;
        if constexpr (__is_same(OUT, float))
          C[(row0 + r) * ldc + col] = val;
        else
          C[(row0 + r) * ldc + col] = f2bf(val);
      }
    }
  }
}

// ---------------- Flash attention v5: R6 staging + 2q x 2d PV split -----------------
__global__ __launch_bounds__(256) void attn_kernel(const unsigned short* __restrict__ qkv,
                                                   const float* __restrict__ ab,
                                                   unsigned short* __restrict__ attn_out) {
  __shared__ float lut[1024];
  __shared__ unsigned short vt[128][72];      // V^T tile, SGM-swizzled cols
  __shared__ unsigned short k_sm[64][40];
  __shared__ unsigned short p_sm[4][16][72];
  __shared__ float l_sm[64];

  int tid = threadIdx.x;
  int lane = tid & 63, w = tid >> 6;
  int quad = lane >> 4, l15 = lane & 15;
  int wq = w & 1, wd = w >> 1;
  int qb = blockIdx.x;
  int bh = blockIdx.y;
  int b = bh >> 4, h = bh & 15;
  const unsigned short* base = qkv + (size_t)b * NSEQ * LDQKV + h * 192;

  for (int t = tid; t < 1024; t += 256) lut[t] = ab[h * 1024 + t];

  // Q fragment: A[m=lane&15][k=quad*8+j]
  int qr = qb * 64 + w * 16 + l15;
  bf16x8 qf = *(const bf16x8*)(base + (size_t)qr * LDQKV + quad * 8);

  f32x4 accO[2][4] = {};
  float l_r[4] = {0.f, 0.f, 0.f, 0.f};

  int pcol_lo = (l15 & 8) | SGM(l15 & 7);
  int kkey = tid >> 2, kch = tid & 3;

  // prologue prefetch (tile 0)
  uint4 vreg[4];
  uint4 kreg;
#pragma unroll
  for (int i = 0; i < 4; i++) {
    int c = tid + i * 256;
    int m = c >> 4, c8 = c & 15;
    vreg[i] = *(const uint4*)(base + (size_t)m * LDQKV + 64 + c8 * 8);
  }
  kreg = *(const uint4*)(base + (size_t)kkey * LDQKV + 32 + kch * 8);

  for (int kt = 0; kt < 16; kt++) {
    __syncthreads();  // prior tile's readers done
    // stage regs -> LDS (SGM scatter for V^T)
#pragma unroll
    for (int i = 0; i < 4; i++) {
      int c = tid + i * 256;
      int m = c >> 4, c8 = c & 15;
      const unsigned short* pv = (const unsigned short*)&vreg[i];
      int col = (((m >> 3) ^ (c8 & 7)) << 3) | SGM(m & 7);
#pragma unroll
      for (int e = 0; e < 8; e++) vt[c8 * 8 + e][col] = pv[e];
    }
    *(uint4*)&k_sm[kkey][kch * 8] = kreg;
    __syncthreads();  // staged

    if (kt < 15) {
#pragma unroll
      for (int i = 0; i < 4; i++) {
        int c = tid + i * 256;
        int m = c >> 4, c8 = c & 15;
        vreg[i] = *(const uint4*)(base + (size_t)((kt + 1) * 64 + m) * LDQKV + 64 + c8 * 8);
      }
      kreg = *(const uint4*)(base + (size_t)((kt + 1) * 64 + kkey) * LDQKV + 32 + kch * 8);
    }

    // S = Q K^T
    f32x4 s[4];
#pragma unroll
    for (int nb = 0; nb < 4; nb++) {
      bf16x8 kf = *(const bf16x8*)&k_sm[nb * 16 + l15][quad * 8];
      f32x4 z = {};
      s[nb] = __builtin_amdgcn_mfma_f32_16x16x32_bf16(qf, kf, z, 0, 0, 0);
    }

    // scale + analytic bias + exp; l partials; write P (SGM-permuted cols)
#pragma unroll
    for (int nb = 0; nb < 4; nb++) {
      int cc = kt * 64 + nb * 16 + l15;
      int cx = cc >> 5, cy = cc & 31;
#pragma unroll
      for (int r = 0; r < 4; r++) {
        int rr = qb * 64 + w * 16 + quad * 4 + r;
        int dx = (rr >> 5) - cx; dx = dx < 0 ? -dx : dx;
        int dy = (rr & 31) - cy; dy = dy < 0 ? -dy : dy;
        float p = __expf(fmaf(s[nb][r], SCALE_, lut[dx * 32 + dy]));
        l_r[r] += p;
        p_sm[w][quad * 4 + r][nb * 16 + pcol_lo] = f2bf(p);
      }
    }
    __syncthreads();  // p_sm visible

    // O += P V : wave (wq, wd) covers q-groups {2wq,2wq+1} x d-blocks {4wd..4wd+3}
#pragma unroll
    for (int kc = 0; kc < 2; kc++) {
      bf16x8 pf[2];
#pragma unroll
      for (int g = 0; g < 2; g++)
        pf[g] = *(const bf16x8*)&p_sm[wq * 2 + g][l15][kc * 32 + quad * 8];
#pragma unroll
      for (int j = 0; j < 4; j++) {
        int db = wd * 4 + j;
        int f = (db * 2 + (l15 >> 3)) & 7;
        int colb = ((kc * 4 + quad) ^ f) << 3;
        bf16x8 vf = *(const bf16x8*)&vt[db * 16 + l15][colb];
#pragma unroll
        for (int g = 0; g < 2; g++)
          accO[g][j] = __builtin_amdgcn_mfma_f32_16x16x32_bf16(pf[g], vf, accO[g][j], 0, 0, 0);
      }
    }
  }
  // share l across waves (wave w computed rows w*16..+16)
#pragma unroll
  for (int r = 0; r < 4; r++) {
#pragma unroll
    for (int off = 8; off; off >>= 1) l_r[r] += __shfl_xor(l_r[r], off, 16);
  }
  if (l15 == 0) {
#pragma unroll
    for (int r = 0; r < 4; r++) l_sm[w * 16 + quad * 4 + r] = l_r[r];
  }
  __syncthreads();
  // epilogue
#pragma unroll
  for (int g = 0; g < 2; g++) {
#pragma unroll
    for (int r = 0; r < 4; r++) {
      int row16 = (wq * 2 + g) * 16 + quad * 4 + r;
      float inv = 1.f / l_sm[row16];
      int row = qb * 64 + row16;
      size_t obase = ((size_t)b * NSEQ + row) * DH_ + h * DD_;
#pragma unroll
      for (int j = 0; j < 4; j++)
        attn_out[obase + (wd * 4 + j) * 16 + l15] = f2bf(accO[g][j][r] * inv);
    }
  }
}

extern "C" void kernel_launch(void* const* d_in, const int* in_sizes, int n_in,
                              void* d_out, int out_size, void* d_ws, size_t ws_size,
                              hipStream_t stream) {
  const float* x      = (const float*)d_in[0];
  const float* gamma  = (const float*)d_in[1];
  const float* beta   = (const float*)d_in[2];
  const float* qkv_w  = (const float*)d_in[3];
  const float* qkv_b  = (const float*)d_in[4];
  const float* proj_w = (const float*)d_in[5];
  const float* proj_b = (const float*)d_in[6];
  const float* ab     = (const float*)d_in[7];

  char* ws = (char*)d_ws;
  unsigned short* xn      = (unsigned short*)(ws);                          // 16 MiB @0
  unsigned short* wqkv    = (unsigned short*)(ws + (size_t)16 * 1048576);   //  3 MiB @16
  unsigned short* wproj   = (unsigned short*)(ws + (size_t)19 * 1048576);   //  2 MiB @19
  unsigned short* qkv     = (unsigned short*)(ws + (size_t)21 * 1048576);   // 96 MiB @21
  unsigned short* attnout = (unsigned short*)(ws + (size_t)117 * 1048576);  // 64 MiB @117
  float* out = (float*)d_out;                                               // fp32 output

  cvt_kernel<<<dim3(6144), dim3(256), 0, stream>>>(qkv_w, wqkv, 3072 * 512);
  cvt_kernel<<<dim3(4096), dim3(256), 0, stream>>>(proj_w, wproj, 512 * 2048);
  ln_kernel<<<dim3(16384), dim3(256), 0, stream>>>(x, gamma, beta, xn);
  gemm_gll<unsigned short><<<dim3(24, 128), dim3(256), 0, stream>>>(xn, 512, wqkv, 512, qkv_b, qkv, 3072, 512);
  attn_kernel<<<dim3(16, 256), dim3(256), 0, stream>>>(qkv, ab, attnout);
  gemm_gll<float><<<dim3(4, 128), dim3(256), 0, stream>>>(attnout, 2048, wproj, 2048, proj_b, out, 512, 2048);
}